// Round 1
// baseline (2170.368 us; speedup 1.0000x reference)
//
#include <hip/hip_runtime.h>
#include <math.h>

#define NB 8192
#define NN 20
#define DD 128
#define HH 8
#define FFD 512

// ---------------- prep: repack conv weights + fuse bias tables ----------------
// Wc layout: Wc[(k*128+din)*384 + c], c in [0,128)=q dout, [128,256)=k, [256,384)=v
// biasT[h*400 + n*20 + m] = rel_table[(n-m+19)*8 + h] + gbias[h][n][m]*alpha
__global__ __launch_bounds__(256) void prep_kernel(
    const float* __restrict__ wq, const float* __restrict__ wk, const float* __restrict__ wv,
    const float* __restrict__ rel, const float* __restrict__ gb, const float* __restrict__ alpha,
    float* __restrict__ Wc, float* __restrict__ biasT)
{
  int blk = blockIdx.x;
  if (blk < 384) {
    int rin = blk;
    int kk = rin >> 7, din = rin & 127;
    for (int c = threadIdx.x; c < 384; c += blockDim.x) {
      int which = c >> 7, dout = c & 127;
      const float* w = (which == 0) ? wq : (which == 1) ? wk : wv;
      Wc[rin * 384 + c] = w[(dout * 128 + din) * 3 + kk];
    }
  } else {
    int h = blk - 384;  // 0..7
    float a = alpha[0];
    for (int i = threadIdx.x; i < 400; i += blockDim.x) {
      int n = i / 20, m = i % 20;
      biasT[h * 400 + i] = rel[(n - m + 19) * 8 + h] + gb[h * 400 + i] * a;
    }
  }
}

__device__ __forceinline__ float gelu_exact(float v) {
  return 0.5f * v * (1.f + erff(v * 0.70710678118654752440f));
}

// ---------------- fused encoder block: one workgroup per batch element ----------------
__global__ __launch_bounds__(256) void fused_kernel(
    const float* __restrict__ x,
    const float* __restrict__ Wc, const float* __restrict__ biasT,
    const float* __restrict__ lnq_w, const float* __restrict__ lnq_b,
    const float* __restrict__ lnk_w, const float* __restrict__ lnk_b,
    const float* __restrict__ lnv_w, const float* __restrict__ lnv_b,
    const float* __restrict__ wo, const float* __restrict__ bo,
    const float* __restrict__ w1, const float* __restrict__ b1,
    const float* __restrict__ w2, const float* __restrict__ b2,
    const float* __restrict__ n1w, const float* __restrict__ n1b,
    const float* __restrict__ n2w, const float* __restrict__ n2b,
    float* __restrict__ out)
{
  __shared__ float xs[NN * DD];   // 10 KB: x, later xr
  __shared__ float U[NN * FFD];   // 40 KB union: {q,k,v,ctx} -> {ffn h}
  float* qs = U;
  float* ks = U + 2560;
  float* vs = U + 5120;
  float* cx = U + 7680;

  const int t = threadIdx.x;
  const int b = blockIdx.x;
  const float* xb = x + (size_t)b * (NN * DD);

  // ---- S0: load x tile (coalesced float4) ----
  {
    const float4* src = (const float4*)xb;
    float4* dst = (float4*)xs;
    #pragma unroll
    for (int i = 0; i < (NN * DD / 4) / 256 + 1; ++i) {
      int idx = t + i * 256;
      if (idx < NN * DD / 4) dst[idx] = src[idx];
    }
  }
  __syncthreads();

  const int dout = t & 127;
  const int half = t >> 7;
  const int n0 = half * 10;

  // ---- S1: conv1d QKV as matmul (rows n0..n0+9, col dout, K-dim 384) ----
  {
    float aq[10], ak[10], av[10];
    #pragma unroll
    for (int r = 0; r < 10; ++r) { aq[r] = 0.f; ak[r] = 0.f; av[r] = 0.f; }
    for (int din = 0; din < 128; ++din) {
      float xv[12];
      #pragma unroll
      for (int j = 0; j < 12; ++j) {
        int m = n0 - 1 + j;
        xv[j] = (m >= 0 && m < NN) ? xs[m * DD + din] : 0.f;
      }
      #pragma unroll
      for (int kk = 0; kk < 3; ++kk) {
        const float* wrow = Wc + (kk * 128 + din) * 384;
        float wqv = wrow[dout];
        float wkv = wrow[128 + dout];
        float wvv = wrow[256 + dout];
        #pragma unroll
        for (int r = 0; r < 10; ++r) {
          float xx = xv[r + kk];
          aq[r] = fmaf(xx, wqv, aq[r]);
          ak[r] = fmaf(xx, wkv, ak[r]);
          av[r] = fmaf(xx, wvv, av[r]);
        }
      }
    }
    #pragma unroll
    for (int r = 0; r < 10; ++r) {
      qs[(n0 + r) * DD + dout] = aq[r];
      ks[(n0 + r) * DD + dout] = ak[r];
      vs[(n0 + r) * DD + dout] = av[r];
    }
  }
  __syncthreads();

  // ---- S1b: LayerNorm + residual for q,k,v (in place) ----
  {
    int warp = t >> 6, lane = t & 63;
    for (int rp = warp; rp < 60; rp += 4) {
      int proj = rp / 20, n = rp % 20;
      float* buf = U + proj * 2560 + n * DD;
      float v0 = buf[lane], v1 = buf[lane + 64];
      float s = v0 + v1, sq = v0 * v0 + v1 * v1;
      #pragma unroll
      for (int off = 32; off > 0; off >>= 1) {
        s  += __shfl_xor(s, off);
        sq += __shfl_xor(sq, off);
      }
      float mean = s * (1.f / 128.f);
      float var  = sq * (1.f / 128.f) - mean * mean;
      float inv  = rsqrtf(var + 1e-5f);
      const float* gw = (proj == 0) ? lnq_w : (proj == 1) ? lnk_w : lnv_w;
      const float* gb = (proj == 0) ? lnq_b : (proj == 1) ? lnk_b : lnv_b;
      buf[lane]      = xs[n * DD + lane]      + (v0 - mean) * inv * gw[lane]      + gb[lane];
      buf[lane + 64] = xs[n * DD + lane + 64] + (v1 - mean) * inv * gw[lane + 64] + gb[lane + 64];
    }
  }
  __syncthreads();

  // ---- S2: attention (one thread per (head, query-row)) ----
  if (t < HH * NN) {
    int h = t / NN, n = t % NN;
    float qv[16];
    #pragma unroll
    for (int j = 0; j < 16; ++j) qv[j] = qs[n * DD + h * 16 + j];
    const float* bias = biasT + h * 400 + n * 20;
    float p[20];
    float mx = -1e30f;
    #pragma unroll
    for (int m = 0; m < 20; ++m) {
      float s = 0.f;
      #pragma unroll
      for (int j = 0; j < 16; ++j) s = fmaf(qv[j], ks[m * DD + h * 16 + j], s);
      s = s * 0.25f + bias[m];
      p[m] = s;
      mx = fmaxf(mx, s);
    }
    float sum = 0.f;
    #pragma unroll
    for (int m = 0; m < 20; ++m) { p[m] = expf(p[m] - mx); sum += p[m]; }
    float rs = 1.f / sum;
    #pragma unroll
    for (int j = 0; j < 16; ++j) {
      float c = 0.f;
      #pragma unroll
      for (int m = 0; m < 20; ++m) c = fmaf(p[m], vs[m * DD + h * 16 + j], c);
      cx[n * DD + h * 16 + j] = c * rs;
    }
  }
  __syncthreads();

  // ---- S3: attn_out = ctx @ wo + bo; pre-LN = x + attn_out -> qs slot ----
  {
    float acc[10];
    #pragma unroll
    for (int r = 0; r < 10; ++r) acc[r] = 0.f;
    for (int din = 0; din < 128; ++din) {
      float wv = wo[din * 128 + dout];
      #pragma unroll
      for (int r = 0; r < 10; ++r)
        acc[r] = fmaf(cx[(n0 + r) * DD + din], wv, acc[r]);
    }
    float bov = bo[dout];
    #pragma unroll
    for (int r = 0; r < 10; ++r) {
      int n = n0 + r;
      qs[n * DD + dout] = xs[n * DD + dout] + acc[r] + bov;
    }
  }
  __syncthreads();

  // ---- S3b: xr = LN(x + attn_out) -> xs ----
  {
    int warp = t >> 6, lane = t & 63;
    for (int n = warp; n < 20; n += 4) {
      float v0 = qs[n * DD + lane], v1 = qs[n * DD + lane + 64];
      float s = v0 + v1, sq = v0 * v0 + v1 * v1;
      #pragma unroll
      for (int off = 32; off > 0; off >>= 1) {
        s  += __shfl_xor(s, off);
        sq += __shfl_xor(sq, off);
      }
      float mean = s * (1.f / 128.f);
      float var  = sq * (1.f / 128.f) - mean * mean;
      float inv  = rsqrtf(var + 1e-5f);
      xs[n * DD + lane]      = (v0 - mean) * inv * n1w[lane]      + n1b[lane];
      xs[n * DD + lane + 64] = (v1 - mean) * inv * n1w[lane + 64] + n1b[lane + 64];
    }
  }
  __syncthreads();

  // ---- S4: h = gelu(xr @ w1 + b1) -> U (20 x 512); thread owns cols t and t+256 ----
  {
    float a0[20], a1[20];
    #pragma unroll
    for (int n = 0; n < 20; ++n) { a0[n] = 0.f; a1[n] = 0.f; }
    for (int din = 0; din < 128; ++din) {
      float w0  = w1[din * FFD + t];
      float w1v = w1[din * FFD + t + 256];
      #pragma unroll
      for (int n = 0; n < 20; ++n) {
        float xv = xs[n * DD + din];
        a0[n] = fmaf(xv, w0,  a0[n]);
        a1[n] = fmaf(xv, w1v, a1[n]);
      }
    }
    float bb0 = b1[t], bb1 = b1[t + 256];
    #pragma unroll
    for (int n = 0; n < 20; ++n) {
      U[n * FFD + t]       = gelu_exact(a0[n] + bb0);
      U[n * FFD + t + 256] = gelu_exact(a1[n] + bb1);
    }
  }
  __syncthreads();

  // ---- S5: ffn = h @ w2 + b2; pre-LN2 = xr + ffn ----
  {
    float acc[10];
    #pragma unroll
    for (int r = 0; r < 10; ++r) acc[r] = 0.f;
    for (int f4 = 0; f4 < FFD / 4; ++f4) {
      int ff = f4 * 4;
      float wa = w2[(ff + 0) * 128 + dout];
      float wb = w2[(ff + 1) * 128 + dout];
      float wc = w2[(ff + 2) * 128 + dout];
      float wd = w2[(ff + 3) * 128 + dout];
      #pragma unroll
      for (int r = 0; r < 10; ++r) {
        float4 hv = *(const float4*)&U[(n0 + r) * FFD + ff];
        acc[r] = fmaf(hv.x, wa, fmaf(hv.y, wb, fmaf(hv.z, wc, fmaf(hv.w, wd, acc[r]))));
      }
    }
    __syncthreads();  // all h reads done before overwriting U
    float b2v = b2[dout];
    #pragma unroll
    for (int r = 0; r < 10; ++r) {
      int n = n0 + r;
      U[n * DD + dout] = xs[n * DD + dout] + acc[r] + b2v;
    }
  }
  __syncthreads();

  // ---- S5b: out = LN(xr + ffn) ----
  {
    int warp = t >> 6, lane = t & 63;
    float* ob = out + (size_t)b * (NN * DD);
    for (int n = warp; n < 20; n += 4) {
      float v0 = U[n * DD + lane], v1 = U[n * DD + lane + 64];
      float s = v0 + v1, sq = v0 * v0 + v1 * v1;
      #pragma unroll
      for (int off = 32; off > 0; off >>= 1) {
        s  += __shfl_xor(s, off);
        sq += __shfl_xor(sq, off);
      }
      float mean = s * (1.f / 128.f);
      float var  = sq * (1.f / 128.f) - mean * mean;
      float inv  = rsqrtf(var + 1e-5f);
      ob[n * DD + lane]      = (v0 - mean) * inv * n2w[lane]      + n2b[lane];
      ob[n * DD + lane + 64] = (v1 - mean) * inv * n2w[lane + 64] + n2b[lane + 64];
    }
  }
}

extern "C" void kernel_launch(void* const* d_in, const int* in_sizes, int n_in,
                              void* d_out, int out_size, void* d_ws, size_t ws_size,
                              hipStream_t stream) {
  const float* x     = (const float*)d_in[0];
  const float* wq    = (const float*)d_in[1];
  const float* wk    = (const float*)d_in[2];
  const float* wv    = (const float*)d_in[3];
  const float* lnq_w = (const float*)d_in[4];
  const float* lnq_b = (const float*)d_in[5];
  const float* lnk_w = (const float*)d_in[6];
  const float* lnk_b = (const float*)d_in[7];
  const float* lnv_w = (const float*)d_in[8];
  const float* lnv_b = (const float*)d_in[9];
  const float* rel   = (const float*)d_in[10];
  const float* gb    = (const float*)d_in[11];
  const float* alpha = (const float*)d_in[12];
  const float* wo    = (const float*)d_in[13];
  const float* bo    = (const float*)d_in[14];
  const float* w1    = (const float*)d_in[15];
  const float* b1    = (const float*)d_in[16];
  const float* w2    = (const float*)d_in[17];
  const float* b2    = (const float*)d_in[18];
  const float* n1w   = (const float*)d_in[19];
  const float* n1b   = (const float*)d_in[20];
  const float* n2w   = (const float*)d_in[21];
  const float* n2b   = (const float*)d_in[22];
  float* out = (float*)d_out;

  float* Wc    = (float*)d_ws;             // 384*384 floats
  float* biasT = Wc + 384 * 384;           // 8*20*20 floats

  hipLaunchKernelGGL(prep_kernel, dim3(392), dim3(256), 0, stream,
                     wq, wk, wv, rel, gb, alpha, Wc, biasT);
  hipLaunchKernelGGL(fused_kernel, dim3(NB), dim3(256), 0, stream,
                     x, Wc, biasT, lnq_w, lnq_b, lnk_w, lnk_b, lnv_w, lnv_b,
                     wo, bo, w1, b1, w2, b2, n1w, n1b, n2w, n2b, out);
}

// Round 2
// 381.886 us; speedup vs baseline: 5.6833x; 5.6833x over previous
//
#include <hip/hip_runtime.h>
#include <hip/hip_bf16.h>
#include <math.h>

#define NB 8192
#define NN 20
#define DD 128
#define HH 8
#define FFD 512

typedef __attribute__((ext_vector_type(8))) short bf16x8;
typedef __attribute__((ext_vector_type(4))) float f32x4;

__device__ __forceinline__ unsigned short f2bf(float f) {
  union { __hip_bfloat16 h; unsigned short u; } cv; cv.h = __float2bfloat16(f); return cv.u;
}
__device__ __forceinline__ float bf2f(unsigned short u) {
  union { unsigned short u; __hip_bfloat16 h; } cv; cv.u = u; return __bfloat162float(cv.h);
}
__device__ __forceinline__ float gelu_t(float v) {
  // tanh-form gelu; |err vs exact erf| ~1e-3, NaN-safe for e->inf
  float u = v * (0.7978845608f + 0.0356774081f * v * v);
  float e = __expf(2.f * u);
  float th = 1.f - 2.f / (e + 1.f);
  return 0.5f * v * (1.f + th);
}

// ======================= NEW PATH: prep (weight frag swizzle + bias fuse) =======================
// Frag layout for B operand of mfma_f32_16x16x32_bf16: B[k][c], lane=16*(k/8 grp)+c15,
// each lane holds 8 contiguous k. Stored as [nt][kc][lane][8] -> one coalesced 1KB load/frag.
__global__ __launch_bounds__(256) void prep2(
    const float* __restrict__ wq, const float* __restrict__ wk, const float* __restrict__ wv,
    const float* __restrict__ w1, const float* __restrict__ w2, const float* __restrict__ wo,
    const float* __restrict__ rel, const float* __restrict__ gb, const float* __restrict__ alpha,
    unsigned short* __restrict__ WcF, unsigned short* __restrict__ w1F,
    unsigned short* __restrict__ w2F, unsigned short* __restrict__ woF,
    float* __restrict__ biasT)
{
  int bid = blockIdx.x, t = threadIdx.x;
  if (bid < 288) {            // conv: K=384 (kc 12), N=384 (nt 24)
    int nt = bid / 12, kc = bid % 12;
    for (int i = t; i < 512; i += 256) {
      int lane = i >> 3, j = i & 7;
      int k = kc * 32 + (lane >> 4) * 8 + j;
      int c = nt * 16 + (lane & 15);
      int kk = k >> 7, din = k & 127;
      int which = c >> 7, dout = c & 127;
      const float* w = (which == 0) ? wq : (which == 1) ? wk : wv;
      WcF[((nt * 12 + kc) * 64 + lane) * 8 + j] = f2bf(w[(dout * 128 + din) * 3 + kk]);
    }
  } else if (bid < 416) {     // w1: K=128 (kc 4), N=512 (nt 32)
    int tt = bid - 288; int nt = tt / 4, kc = tt % 4;
    for (int i = t; i < 512; i += 256) {
      int lane = i >> 3, j = i & 7;
      int k = kc * 32 + (lane >> 4) * 8 + j;
      int c = nt * 16 + (lane & 15);
      w1F[((nt * 4 + kc) * 64 + lane) * 8 + j] = f2bf(w1[k * 512 + c]);
    }
  } else if (bid < 544) {     // w2: K=512 (kc 16), N=128 (nt 8)
    int tt = bid - 416; int nt = tt / 16, kc = tt % 16;
    for (int i = t; i < 512; i += 256) {
      int lane = i >> 3, j = i & 7;
      int k = kc * 32 + (lane >> 4) * 8 + j;
      int c = nt * 16 + (lane & 15);
      w2F[((nt * 16 + kc) * 64 + lane) * 8 + j] = f2bf(w2[k * 128 + c]);
    }
  } else if (bid < 576) {     // wo: K=128 (kc 4), N=128 (nt 8)
    int tt = bid - 544; int nt = tt / 4, kc = tt % 4;
    for (int i = t; i < 512; i += 256) {
      int lane = i >> 3, j = i & 7;
      int k = kc * 32 + (lane >> 4) * 8 + j;
      int c = nt * 16 + (lane & 15);
      woF[((nt * 4 + kc) * 64 + lane) * 8 + j] = f2bf(wo[k * 128 + c]);
    }
  } else {                    // bias fuse
    int h = bid - 576; float a = alpha[0];
    for (int i = t; i < 400; i += 256) {
      int n = i / 20, m = i % 20;
      biasT[h * 400 + i] = rel[(n - m + 19) * 8 + h] + gb[h * 400 + i] * a;
    }
  }
}

// ======================= NEW PATH: fused conv-QKV + attention + wo + LN1 =======================
// 2 elements/block, 256 thr (4 waves). Rows 0..39 real, padded to 48 (3 M-tiles).
// LDS union (81,920B/2 blocks-per-CU budget -> 80,832B used):
//   qkv  [3][2][20][136] bf16 @ 0      (32640)
//   ctx  [2][20][136]    bf16 @ 32640  (10880)
//   xA   [2][22][136]    bf16 @ 43520  (11968)  zero-padded halo rows
//   scr  [48][132]       f32  @ 55488  (25344)
__global__ __launch_bounds__(256, 2) void fused_ab(
    const float* __restrict__ x,
    const unsigned short* __restrict__ WcF, const unsigned short* __restrict__ woF,
    const float* __restrict__ biasT,
    const float* __restrict__ lnq_w, const float* __restrict__ lnq_b,
    const float* __restrict__ lnk_w, const float* __restrict__ lnk_b,
    const float* __restrict__ lnv_w, const float* __restrict__ lnv_b,
    const float* __restrict__ bo,
    const float* __restrict__ n1w, const float* __restrict__ n1b,
    unsigned short* __restrict__ xr)
{
  __shared__ __align__(16) char smem[80832];
  unsigned short* qkv = (unsigned short*)smem;
  unsigned short* ctx = (unsigned short*)(smem + 32640);
  unsigned short* xA  = (unsigned short*)(smem + 43520);
  float* scr = (float*)(smem + 55488);

  const int t = threadIdx.x;
  const int w = t >> 6, l = t & 63;
  const int l15 = l & 15, l4 = l >> 4;
  const int eb = blockIdx.x * 2;
  const float* xg = x + (size_t)eb * (NN * DD);

  // row->element mapping for M-tiles (rows 40..47 clamped to a real row; results discarded)
  int emap[3], nmap[3];
  #pragma unroll
  for (int mt = 0; mt < 3; ++mt) {
    int g = mt * 16 + l15;
    int e = g / 20, n = g - e * 20;
    if (e > 1) { e = 1; n = 19; }
    emap[mt] = e; nmap[mt] = n;
  }

  // ---- P0: x -> xA bf16, halo rows zeroed ----
  for (int i = t; i < 2 * 2 * 136; i += 256) {
    int e = i / 272, rr = i % 272; int pr = rr / 136, c = rr % 136;
    xA[(e * 22 + pr * 21) * 136 + c] = 0;
  }
  for (int i = t; i < 1280; i += 256) {
    int e = i / 640, r2 = i % 640; int n = r2 / 32, c4 = r2 % 32;
    float4 v = *(const float4*)(xg + e * 2560 + n * 128 + c4 * 4);
    unsigned short* dst = &xA[(e * 22 + n + 1) * 136 + c4 * 4];
    ushort4 pk; pk.x = f2bf(v.x); pk.y = f2bf(v.y); pk.z = f2bf(v.z); pk.w = f2bf(v.w);
    *(ushort4*)dst = pk;
  }
  __syncthreads();

  // ---- conv1d QKV as MFMA GEMM, one projection at a time (scratch reuse) ----
  for (int p = 0; p < 3; ++p) {
    const float* lw = (p == 0) ? lnq_w : (p == 1) ? lnk_w : lnv_w;
    const float* lb = (p == 0) ? lnq_b : (p == 1) ? lnk_b : lnv_b;
    f32x4 acc[3][2];
    #pragma unroll
    for (int mt = 0; mt < 3; ++mt)
      #pragma unroll
      for (int i = 0; i < 2; ++i) acc[mt][i] = (f32x4){0.f, 0.f, 0.f, 0.f};

    for (int kc = 0; kc < 12; ++kc) {
      int kk = kc >> 2;
      int din0 = (kc & 3) * 32 + l4 * 8;
      bf16x8 a[3], b[2];
      #pragma unroll
      for (int mt = 0; mt < 3; ++mt)
        a[mt] = *(const bf16x8*)&xA[(emap[mt] * 22 + nmap[mt] + kk) * 136 + din0];
      #pragma unroll
      for (int i = 0; i < 2; ++i) {
        int ntg = p * 8 + w * 2 + i;
        b[i] = *(const bf16x8*)&WcF[((ntg * 12 + kc) * 64 + l) * 8];
      }
      #pragma unroll
      for (int mt = 0; mt < 3; ++mt)
        #pragma unroll
        for (int i = 0; i < 2; ++i)
          acc[mt][i] = __builtin_amdgcn_mfma_f32_16x16x32_bf16(a[mt], b[i], acc[mt][i], 0, 0, 0);
    }
    // D -> scratch (m89 layout: col=lane&15, row=(lane>>4)*4+j)
    #pragma unroll
    for (int mt = 0; mt < 3; ++mt)
      #pragma unroll
      for (int i = 0; i < 2; ++i) {
        int col = (w * 2 + i) * 16 + l15;
        int rbase = mt * 16 + l4 * 4;
        #pragma unroll
        for (int j = 0; j < 4; ++j) scr[(rbase + j) * 132 + col] = acc[mt][i][j];
      }
    __syncthreads();
    // LN + residual -> qkv bf16 (q gets 0.25 folded in)
    for (int r = w; r < 40; r += 4) {
      float v0 = scr[r * 132 + l], v1 = scr[r * 132 + 64 + l];
      float s = v0 + v1, sq = v0 * v0 + v1 * v1;
      #pragma unroll
      for (int off = 32; off > 0; off >>= 1) { s += __shfl_xor(s, off); sq += __shfl_xor(sq, off); }
      float mean = s * (1.f / 128.f);
      float var  = sq * (1.f / 128.f) - mean * mean;
      float inv  = rsqrtf(var + 1e-5f);
      int e = r / 20, n = r % 20;
      float x0 = xg[e * 2560 + n * 128 + l], x1 = xg[e * 2560 + n * 128 + 64 + l];
      float o0 = x0 + (v0 - mean) * inv * lw[l] + lb[l];
      float o1 = x1 + (v1 - mean) * inv * lw[64 + l] + lb[64 + l];
      if (p == 0) { o0 *= 0.25f; o1 *= 0.25f; }
      qkv[((p * 2 + e) * 20 + n) * 136 + l] = f2bf(o0);
      qkv[((p * 2 + e) * 20 + n) * 136 + 64 + l] = f2bf(o1);
    }
    __syncthreads();
  }

  // ---- attention (fp32 VALU), per-wave balanced: 80 rows/wave of 320 total ----
  #pragma unroll
  for (int ii = 0; ii < 2; ++ii) {
    int i = (ii == 0) ? l : (l + 64);
    if (i < 80) {
      int rid = w * 80 + i;
      int e = rid / 160, hh = (rid / 20) % 8, n = rid % 20;
      float q[16];
      {
        const unsigned short* qr = &qkv[(e * 20 + n) * 136 + hh * 16];
        bf16x8 qa = *(const bf16x8*)qr, qb = *(const bf16x8*)(qr + 8);
        #pragma unroll
        for (int j = 0; j < 8; ++j) { q[j] = bf2f((unsigned short)qa[j]); q[8 + j] = bf2f((unsigned short)qb[j]); }
      }
      float bias[20];
      const float* bp = &biasT[(hh * 20 + n) * 20];
      #pragma unroll
      for (int m4 = 0; m4 < 5; ++m4) {
        float4 bv = *(const float4*)(bp + m4 * 4);
        bias[m4 * 4] = bv.x; bias[m4 * 4 + 1] = bv.y; bias[m4 * 4 + 2] = bv.z; bias[m4 * 4 + 3] = bv.w;
      }
      float pm[20]; float mx = -1e30f;
      #pragma unroll
      for (int m = 0; m < 20; ++m) {
        const unsigned short* kr = &qkv[((2 + e) * 20 + m) * 136 + hh * 16];
        bf16x8 ka = *(const bf16x8*)kr, kb = *(const bf16x8*)(kr + 8);
        float s = bias[m];
        #pragma unroll
        for (int j = 0; j < 8; ++j) {
          s = fmaf(q[j], bf2f((unsigned short)ka[j]), s);
          s = fmaf(q[8 + j], bf2f((unsigned short)kb[j]), s);
        }
        pm[m] = s; mx = fmaxf(mx, s);
      }
      float sum = 0.f;
      #pragma unroll
      for (int m = 0; m < 20; ++m) { pm[m] = __expf(pm[m] - mx); sum += pm[m]; }
      float rs = 1.f / sum;
      float c[16];
      #pragma unroll
      for (int j = 0; j < 16; ++j) c[j] = 0.f;
      #pragma unroll
      for (int m = 0; m < 20; ++m) {
        const unsigned short* vr = &qkv[((4 + e) * 20 + m) * 136 + hh * 16];
        bf16x8 va = *(const bf16x8*)vr, vb = *(const bf16x8*)(vr + 8);
        float pv = pm[m];
        #pragma unroll
        for (int j = 0; j < 8; ++j) {
          c[j] = fmaf(pv, bf2f((unsigned short)va[j]), c[j]);
          c[8 + j] = fmaf(pv, bf2f((unsigned short)vb[j]), c[8 + j]);
        }
      }
      bf16x8 c0, c1;
      #pragma unroll
      for (int j = 0; j < 8; ++j) {
        c0[j] = (short)f2bf(c[j] * rs);
        c1[j] = (short)f2bf(c[8 + j] * rs);
      }
      *(bf16x8*)&ctx[(e * 20 + n) * 136 + hh * 16] = c0;
      *(bf16x8*)&ctx[(e * 20 + n) * 136 + hh * 16 + 8] = c1;
    }
  }
  __syncthreads();

  // ---- wo GEMM (ctx @ wo) ----
  {
    f32x4 acc[3][2];
    #pragma unroll
    for (int mt = 0; mt < 3; ++mt)
      #pragma unroll
      for (int i = 0; i < 2; ++i) acc[mt][i] = (f32x4){0.f, 0.f, 0.f, 0.f};
    for (int kc = 0; kc < 4; ++kc) {
      bf16x8 a[3], b[2];
      #pragma unroll
      for (int mt = 0; mt < 3; ++mt)
        a[mt] = *(const bf16x8*)&ctx[(emap[mt] * 20 + nmap[mt]) * 136 + kc * 32 + l4 * 8];
      #pragma unroll
      for (int i = 0; i < 2; ++i) {
        int ntg = w * 2 + i;
        b[i] = *(const bf16x8*)&woF[((ntg * 4 + kc) * 64 + l) * 8];
      }
      #pragma unroll
      for (int mt = 0; mt < 3; ++mt)
        #pragma unroll
        for (int i = 0; i < 2; ++i)
          acc[mt][i] = __builtin_amdgcn_mfma_f32_16x16x32_bf16(a[mt], b[i], acc[mt][i], 0, 0, 0);
    }
    #pragma unroll
    for (int mt = 0; mt < 3; ++mt)
      #pragma unroll
      for (int i = 0; i < 2; ++i) {
        int col = (w * 2 + i) * 16 + l15;
        int rbase = mt * 16 + l4 * 4;
        #pragma unroll
        for (int j = 0; j < 4; ++j) scr[(rbase + j) * 132 + col] = acc[mt][i][j];
      }
  }
  __syncthreads();

  // ---- LN1(x + attn_out + bo) -> xr bf16 (global) ----
  for (int r = w; r < 40; r += 4) {
    int e = r / 20, n = r % 20;
    float v0 = scr[r * 132 + l]      + bo[l]      + xg[e * 2560 + n * 128 + l];
    float v1 = scr[r * 132 + 64 + l] + bo[64 + l] + xg[e * 2560 + n * 128 + 64 + l];
    float s = v0 + v1, sq = v0 * v0 + v1 * v1;
    #pragma unroll
    for (int off = 32; off > 0; off >>= 1) { s += __shfl_xor(s, off); sq += __shfl_xor(sq, off); }
    float mean = s * (1.f / 128.f);
    float var  = sq * (1.f / 128.f) - mean * mean;
    float inv  = rsqrtf(var + 1e-5f);
    size_t ro = ((size_t)(eb + e) * 20 + n) * 128;
    xr[ro + l]      = f2bf((v0 - mean) * inv * n1w[l] + n1b[l]);
    xr[ro + 64 + l] = f2bf((v1 - mean) * inv * n1w[64 + l] + n1b[64 + l]);
  }
}

// ======================= NEW PATH: FFN + LN2 =======================
// 32 rows/block (element-agnostic), 256 thr. LDS: xrb [32][136] bf16 (8704) + h [32][520] bf16 (33280).
__global__ __launch_bounds__(256, 3) void ffn_c(
    const unsigned short* __restrict__ xr,
    const unsigned short* __restrict__ w1F, const unsigned short* __restrict__ w2F,
    const float* __restrict__ b1, const float* __restrict__ b2,
    const float* __restrict__ n2w, const float* __restrict__ n2b,
    float* __restrict__ out)
{
  __shared__ __align__(16) char smem[8704 + 33280];
  unsigned short* xrb = (unsigned short*)smem;
  unsigned short* h   = (unsigned short*)(smem + 8704);
  float* sc2          = (float*)(smem + 8704);   // aliases h after barrier

  const int t = threadIdx.x;
  const int w = t >> 6, l = t & 63;
  const int l15 = l & 15, l4 = l >> 4;
  const size_t row0 = (size_t)blockIdx.x * 32;

  for (int i = t; i < 512; i += 256) {   // 32 rows x 16 chunks of 8 bf16
    int r = i >> 4, c8 = i & 15;
    *(bf16x8*)&xrb[r * 136 + c8 * 8] = *(const bf16x8*)&xr[(row0 + r) * 128 + c8 * 8];
  }
  __syncthreads();

  // ---- FFN1: h = gelu(xr @ w1 + b1) ----
  {
    f32x4 acc[2][8];
    #pragma unroll
    for (int mt = 0; mt < 2; ++mt)
      #pragma unroll
      for (int i = 0; i < 8; ++i) acc[mt][i] = (f32x4){0.f, 0.f, 0.f, 0.f};
    for (int kc = 0; kc < 4; ++kc) {
      bf16x8 a[2];
      #pragma unroll
      for (int mt = 0; mt < 2; ++mt)
        a[mt] = *(const bf16x8*)&xrb[(mt * 16 + l15) * 136 + kc * 32 + l4 * 8];
      #pragma unroll
      for (int i = 0; i < 8; ++i) {
        int ntg = w * 8 + i;
        bf16x8 b = *(const bf16x8*)&w1F[((ntg * 4 + kc) * 64 + l) * 8];
        #pragma unroll
        for (int mt = 0; mt < 2; ++mt)
          acc[mt][i] = __builtin_amdgcn_mfma_f32_16x16x32_bf16(a[mt], b, acc[mt][i], 0, 0, 0);
      }
    }
    #pragma unroll
    for (int i = 0; i < 8; ++i) {
      int col = (w * 8 + i) * 16 + l15;
      float b1v = b1[col];
      #pragma unroll
      for (int mt = 0; mt < 2; ++mt)
        #pragma unroll
        for (int j = 0; j < 4; ++j) {
          float v = acc[mt][i][j] + b1v;
          h[(mt * 16 + l4 * 4 + j) * 520 + col] = f2bf(gelu_t(v));
        }
    }
  }
  __syncthreads();

  // ---- FFN2: y = h @ w2 ----
  f32x4 acc2[2][2];
  #pragma unroll
  for (int mt = 0; mt < 2; ++mt)
    #pragma unroll
    for (int i = 0; i < 2; ++i) acc2[mt][i] = (f32x4){0.f, 0.f, 0.f, 0.f};
  for (int kc = 0; kc < 16; ++kc) {
    bf16x8 a[2];
    #pragma unroll
    for (int mt = 0; mt < 2; ++mt)
      a[mt] = *(const bf16x8*)&h[(mt * 16 + l15) * 520 + kc * 32 + l4 * 8];
    #pragma unroll
    for (int i = 0; i < 2; ++i) {
      int ntg = w * 2 + i;
      bf16x8 b = *(const bf16x8*)&w2F[((ntg * 16 + kc) * 64 + l) * 8];
      #pragma unroll
      for (int mt = 0; mt < 2; ++mt)
        acc2[mt][i] = __builtin_amdgcn_mfma_f32_16x16x32_bf16(a[mt], b, acc2[mt][i], 0, 0, 0);
    }
  }
  __syncthreads();   // h fully consumed -> reuse as fp32 scratch

  #pragma unroll
  for (int mt = 0; mt < 2; ++mt)
    #pragma unroll
    for (int i = 0; i < 2; ++i) {
      int col = (w * 2 + i) * 16 + l15;
      int rbase = mt * 16 + l4 * 4;
      #pragma unroll
      for (int j = 0; j < 4; ++j) sc2[(rbase + j) * 132 + col] = acc2[mt][i][j];
    }
  __syncthreads();

  // ---- LN2(xr + ffn + b2) -> out ----
  for (int r = w; r < 32; r += 4) {
    float v0 = sc2[r * 132 + l]      + b2[l]      + bf2f(xrb[r * 136 + l]);
    float v1 = sc2[r * 132 + 64 + l] + b2[64 + l] + bf2f(xrb[r * 136 + 64 + l]);
    float s = v0 + v1, sq = v0 * v0 + v1 * v1;
    #pragma unroll
    for (int off = 32; off > 0; off >>= 1) { s += __shfl_xor(s, off); sq += __shfl_xor(sq, off); }
    float mean = s * (1.f / 128.f);
    float var  = sq * (1.f / 128.f) - mean * mean;
    float inv  = rsqrtf(var + 1e-5f);
    out[(row0 + r) * 128 + l]      = (v0 - mean) * inv * n2w[l] + n2b[l];
    out[(row0 + r) * 128 + 64 + l] = (v1 - mean) * inv * n2w[64 + l] + n2b[64 + l];
  }
}

// ======================= FALLBACK PATH (round-1, known good) =======================
__global__ __launch_bounds__(256) void prep_kernel(
    const float* __restrict__ wq, const float* __restrict__ wk, const float* __restrict__ wv,
    const float* __restrict__ rel, const float* __restrict__ gb, const float* __restrict__ alpha,
    float* __restrict__ Wc, float* __restrict__ biasT)
{
  int blk = blockIdx.x;
  if (blk < 384) {
    int rin = blk; int kk = rin >> 7, din = rin & 127;
    for (int c = threadIdx.x; c < 384; c += blockDim.x) {
      int which = c >> 7, dout = c & 127;
      const float* w = (which == 0) ? wq : (which == 1) ? wk : wv;
      Wc[rin * 384 + c] = w[(dout * 128 + din) * 3 + kk];
    }
  } else {
    int h = blk - 384; float a = alpha[0];
    for (int i = threadIdx.x; i < 400; i += blockDim.x) {
      int n = i / 20, m = i % 20;
      biasT[h * 400 + i] = rel[(n - m + 19) * 8 + h] + gb[h * 400 + i] * a;
    }
  }
}

__device__ __forceinline__ float gelu_exact(float v) {
  return 0.5f * v * (1.f + erff(v * 0.70710678118654752440f));
}

__global__ __launch_bounds__(256) void fused_kernel(
    const float* __restrict__ x,
    const float* __restrict__ Wc, const float* __restrict__ biasT,
    const float* __restrict__ lnq_w, const float* __restrict__ lnq_b,
    const float* __restrict__ lnk_w, const float* __restrict__ lnk_b,
    const float* __restrict__ lnv_w, const float* __restrict__ lnv_b,
    const float* __restrict__ wo, const float* __restrict__ bo,
    const float* __restrict__ w1, const float* __restrict__ b1,
    const float* __restrict__ w2, const float* __restrict__ b2,
    const float* __restrict__ n1w, const float* __restrict__ n1b,
    const float* __restrict__ n2w, const float* __restrict__ n2b,
    float* __restrict__ out)
{
  __shared__ float xs[NN * DD];
  __shared__ float U[NN * FFD];
  float* qs = U; float* ks = U + 2560; float* vs = U + 5120; float* cx = U + 7680;
  const int t = threadIdx.x; const int b = blockIdx.x;
  const float* xb = x + (size_t)b * (NN * DD);
  {
    const float4* src = (const float4*)xb; float4* dst = (float4*)xs;
    #pragma unroll
    for (int i = 0; i < (NN * DD / 4) / 256 + 1; ++i) {
      int idx = t + i * 256; if (idx < NN * DD / 4) dst[idx] = src[idx];
    }
  }
  __syncthreads();
  const int dout = t & 127; const int half = t >> 7; const int n0 = half * 10;
  {
    float aq[10], ak[10], av[10];
    #pragma unroll
    for (int r = 0; r < 10; ++r) { aq[r] = 0.f; ak[r] = 0.f; av[r] = 0.f; }
    for (int din = 0; din < 128; ++din) {
      float xv[12];
      #pragma unroll
      for (int j = 0; j < 12; ++j) {
        int m = n0 - 1 + j; xv[j] = (m >= 0 && m < NN) ? xs[m * DD + din] : 0.f;
      }
      #pragma unroll
      for (int kk = 0; kk < 3; ++kk) {
        const float* wrow = Wc + (kk * 128 + din) * 384;
        float wqv = wrow[dout]; float wkv = wrow[128 + dout]; float wvv = wrow[256 + dout];
        #pragma unroll
        for (int r = 0; r < 10; ++r) {
          float xx = xv[r + kk];
          aq[r] = fmaf(xx, wqv, aq[r]); ak[r] = fmaf(xx, wkv, ak[r]); av[r] = fmaf(xx, wvv, av[r]);
        }
      }
    }
    #pragma unroll
    for (int r = 0; r < 10; ++r) {
      qs[(n0 + r) * DD + dout] = aq[r]; ks[(n0 + r) * DD + dout] = ak[r]; vs[(n0 + r) * DD + dout] = av[r];
    }
  }
  __syncthreads();
  {
    int warp = t >> 6, lane = t & 63;
    for (int rp = warp; rp < 60; rp += 4) {
      int proj = rp / 20, n = rp % 20;
      float* buf = U + proj * 2560 + n * DD;
      float v0 = buf[lane], v1 = buf[lane + 64];
      float s = v0 + v1, sq = v0 * v0 + v1 * v1;
      #pragma unroll
      for (int off = 32; off > 0; off >>= 1) { s += __shfl_xor(s, off); sq += __shfl_xor(sq, off); }
      float mean = s * (1.f / 128.f); float var = sq * (1.f / 128.f) - mean * mean;
      float inv = rsqrtf(var + 1e-5f);
      const float* gw = (proj == 0) ? lnq_w : (proj == 1) ? lnk_w : lnv_w;
      const float* gb2 = (proj == 0) ? lnq_b : (proj == 1) ? lnk_b : lnv_b;
      buf[lane] = xs[n * DD + lane] + (v0 - mean) * inv * gw[lane] + gb2[lane];
      buf[lane + 64] = xs[n * DD + lane + 64] + (v1 - mean) * inv * gw[lane + 64] + gb2[lane + 64];
    }
  }
  __syncthreads();
  if (t < HH * NN) {
    int h = t / NN, n = t % NN;
    float qv[16];
    #pragma unroll
    for (int j = 0; j < 16; ++j) qv[j] = qs[n * DD + h * 16 + j];
    const float* bias = biasT + h * 400 + n * 20;
    float p[20]; float mx = -1e30f;
    #pragma unroll
    for (int m = 0; m < 20; ++m) {
      float s = 0.f;
      #pragma unroll
      for (int j = 0; j < 16; ++j) s = fmaf(qv[j], ks[m * DD + h * 16 + j], s);
      s = s * 0.25f + bias[m]; p[m] = s; mx = fmaxf(mx, s);
    }
    float sum = 0.f;
    #pragma unroll
    for (int m = 0; m < 20; ++m) { p[m] = expf(p[m] - mx); sum += p[m]; }
    float rs = 1.f / sum;
    #pragma unroll
    for (int j = 0; j < 16; ++j) {
      float c = 0.f;
      #pragma unroll
      for (int m = 0; m < 20; ++m) c = fmaf(p[m], vs[m * DD + h * 16 + j], c);
      cx[n * DD + h * 16 + j] = c * rs;
    }
  }
  __syncthreads();
  {
    float acc[10];
    #pragma unroll
    for (int r = 0; r < 10; ++r) acc[r] = 0.f;
    for (int din = 0; din < 128; ++din) {
      float wv = wo[din * 128 + dout];
      #pragma unroll
      for (int r = 0; r < 10; ++r) acc[r] = fmaf(cx[(n0 + r) * DD + din], wv, acc[r]);
    }
    float bov = bo[dout];
    #pragma unroll
    for (int r = 0; r < 10; ++r) { int n = n0 + r; qs[n * DD + dout] = xs[n * DD + dout] + acc[r] + bov; }
  }
  __syncthreads();
  {
    int warp = t >> 6, lane = t & 63;
    for (int n = warp; n < 20; n += 4) {
      float v0 = qs[n * DD + lane], v1 = qs[n * DD + lane + 64];
      float s = v0 + v1, sq = v0 * v0 + v1 * v1;
      #pragma unroll
      for (int off = 32; off > 0; off >>= 1) { s += __shfl_xor(s, off); sq += __shfl_xor(sq, off); }
      float mean = s * (1.f / 128.f); float var = sq * (1.f / 128.f) - mean * mean;
      float inv = rsqrtf(var + 1e-5f);
      xs[n * DD + lane] = (v0 - mean) * inv * n1w[lane] + n1b[lane];
      xs[n * DD + lane + 64] = (v1 - mean) * inv * n1w[lane + 64] + n1b[lane + 64];
    }
  }
  __syncthreads();
  {
    float a0[20], a1[20];
    #pragma unroll
    for (int n = 0; n < 20; ++n) { a0[n] = 0.f; a1[n] = 0.f; }
    for (int din = 0; din < 128; ++din) {
      float w0 = w1[din * FFD + t]; float w1v = w1[din * FFD + t + 256];
      #pragma unroll
      for (int n = 0; n < 20; ++n) {
        float xv = xs[n * DD + din];
        a0[n] = fmaf(xv, w0, a0[n]); a1[n] = fmaf(xv, w1v, a1[n]);
      }
    }
    float bb0 = b1[t], bb1 = b1[t + 256];
    #pragma unroll
    for (int n = 0; n < 20; ++n) {
      U[n * FFD + t] = gelu_exact(a0[n] + bb0);
      U[n * FFD + t + 256] = gelu_exact(a1[n] + bb1);
    }
  }
  __syncthreads();
  {
    float acc[10];
    #pragma unroll
    for (int r = 0; r < 10; ++r) acc[r] = 0.f;
    for (int f4 = 0; f4 < FFD / 4; ++f4) {
      int ff = f4 * 4;
      float wa = w2[(ff + 0) * 128 + dout]; float wb = w2[(ff + 1) * 128 + dout];
      float wc = w2[(ff + 2) * 128 + dout]; float wd = w2[(ff + 3) * 128 + dout];
      #pragma unroll
      for (int r = 0; r < 10; ++r) {
        float4 hv = *(const float4*)&U[(n0 + r) * FFD + ff];
        acc[r] = fmaf(hv.x, wa, fmaf(hv.y, wb, fmaf(hv.z, wc, fmaf(hv.w, wd, acc[r]))));
      }
    }
    __syncthreads();
    float b2v = b2[dout];
    #pragma unroll
    for (int r = 0; r < 10; ++r) { int n = n0 + r; U[n * DD + dout] = xs[n * DD + dout] + acc[r] + b2v; }
  }
  __syncthreads();
  {
    int warp = t >> 6, lane = t & 63;
    float* ob = out + (size_t)b * (NN * DD);
    for (int n = warp; n < 20; n += 4) {
      float v0 = U[n * DD + lane], v1 = U[n * DD + lane + 64];
      float s = v0 + v1, sq = v0 * v0 + v1 * v1;
      #pragma unroll
      for (int off = 32; off > 0; off >>= 1) { s += __shfl_xor(s, off); sq += __shfl_xor(sq, off); }
      float mean = s * (1.f / 128.f); float var = sq * (1.f / 128.f) - mean * mean;
      float inv = rsqrtf(var + 1e-5f);
      ob[n * DD + lane] = (v0 - mean) * inv * n2w[lane] + n2b[lane];
      ob[n * DD + lane + 64] = (v1 - mean) * inv * n2w[lane + 64] + n2b[lane + 64];
    }
  }
}

extern "C" void kernel_launch(void* const* d_in, const int* in_sizes, int n_in,
                              void* d_out, int out_size, void* d_ws, size_t ws_size,
                              hipStream_t stream) {
  const float* x     = (const float*)d_in[0];
  const float* wq    = (const float*)d_in[1];
  const float* wk    = (const float*)d_in[2];
  const float* wv    = (const float*)d_in[3];
  const float* lnq_w = (const float*)d_in[4];
  const float* lnq_b = (const float*)d_in[5];
  const float* lnk_w = (const float*)d_in[6];
  const float* lnk_b = (const float*)d_in[7];
  const float* lnv_w = (const float*)d_in[8];
  const float* lnv_b = (const float*)d_in[9];
  const float* rel   = (const float*)d_in[10];
  const float* gb    = (const float*)d_in[11];
  const float* alpha = (const float*)d_in[12];
  const float* wo    = (const float*)d_in[13];
  const float* bo    = (const float*)d_in[14];
  const float* w1    = (const float*)d_in[15];
  const float* b1    = (const float*)d_in[16];
  const float* w2    = (const float*)d_in[17];
  const float* b2    = (const float*)d_in[18];
  const float* n1w   = (const float*)d_in[19];
  const float* n1b   = (const float*)d_in[20];
  const float* n2w   = (const float*)d_in[21];
  const float* n2b   = (const float*)d_in[22];
  float* out = (float*)d_out;

  const size_t NEED = 602624ULL + 41943040ULL;  // frag weights + biasT + xr(bf16)
  if (ws_size >= NEED) {
    unsigned short* WcF = (unsigned short*)d_ws;     // 147456
    unsigned short* w1F = WcF + 147456;              // 65536
    unsigned short* w2F = w1F + 65536;               // 65536
    unsigned short* woF = w2F + 65536;               // 16384
    float* biasT = (float*)(woF + 16384);            // 3200 f32, byte 589824
    unsigned short* xr = (unsigned short*)((char*)d_ws + 602624);

    hipLaunchKernelGGL(prep2, dim3(584), dim3(256), 0, stream,
                       wq, wk, wv, w1, w2, wo, rel, gb, alpha, WcF, w1F, w2F, woF, biasT);
    hipLaunchKernelGGL(fused_ab, dim3(NB / 2), dim3(256), 0, stream,
                       x, WcF, woF, biasT, lnq_w, lnq_b, lnk_w, lnk_b, lnv_w, lnv_b,
                       bo, n1w, n1b, xr);
    hipLaunchKernelGGL(ffn_c, dim3(NB * NN / 32), dim3(256), 0, stream,
                       xr, w1F, w2F, b1, b2, n2w, n2b, out);
  } else {
    float* Wc    = (float*)d_ws;
    float* biasT = Wc + 384 * 384;
    hipLaunchKernelGGL(prep_kernel, dim3(392), dim3(256), 0, stream,
                       wq, wk, wv, rel, gb, alpha, Wc, biasT);
    hipLaunchKernelGGL(fused_kernel, dim3(NB), dim3(256), 0, stream,
                       x, Wc, biasT, lnq_w, lnq_b, lnk_w, lnk_b, lnv_w, lnv_b,
                       wo, bo, w1, b1, w2, b2, n1w, n1b, n2w, n2b, out);
  }
}

// Round 3
// 364.813 us; speedup vs baseline: 5.9493x; 1.0468x over previous
//
#include <hip/hip_runtime.h>
#include <hip/hip_bf16.h>
#include <math.h>

#define NB 8192
#define NN 20
#define DD 128
#define HH 8
#define FFD 512
#define NROWS (NB * NN)          // 163840 total rows

typedef __attribute__((ext_vector_type(8))) short bf16x8;
typedef __attribute__((ext_vector_type(4))) float f32x4;

__device__ __forceinline__ unsigned short f2bf(float f) {
  union { __hip_bfloat16 h; unsigned short u; } cv; cv.h = __float2bfloat16(f); return cv.u;
}
__device__ __forceinline__ float bf2f(unsigned short u) {
  union { unsigned short u; __hip_bfloat16 h; } cv; cv.u = u; return __bfloat162float(cv.h);
}
__device__ __forceinline__ float gelu_t(float v) {
  float u = v * (0.7978845608f + 0.0356774081f * v * v);
  float e = __expf(2.f * u);
  float th = 1.f - 2.f / (e + 1.f);
  return 0.5f * v * (1.f + th);
}

// ======================= prep: weight frag swizzle + bias fuse =======================
__global__ __launch_bounds__(256) void prep2(
    const float* __restrict__ wq, const float* __restrict__ wk, const float* __restrict__ wv,
    const float* __restrict__ w1, const float* __restrict__ w2, const float* __restrict__ wo,
    const float* __restrict__ rel, const float* __restrict__ gb, const float* __restrict__ alpha,
    unsigned short* __restrict__ WcF, unsigned short* __restrict__ w1F,
    unsigned short* __restrict__ w2F, unsigned short* __restrict__ woF,
    float* __restrict__ biasT)
{
  int bid = blockIdx.x, t = threadIdx.x;
  if (bid < 288) {            // conv: K=384 (kc 12), N=384 (nt 24)
    int nt = bid / 12, kc = bid % 12;
    for (int i = t; i < 512; i += 256) {
      int lane = i >> 3, j = i & 7;
      int k = kc * 32 + (lane >> 4) * 8 + j;
      int c = nt * 16 + (lane & 15);
      int kk = k >> 7, din = k & 127;
      int which = c >> 7, dout = c & 127;
      const float* w = (which == 0) ? wq : (which == 1) ? wk : wv;
      WcF[((nt * 12 + kc) * 64 + lane) * 8 + j] = f2bf(w[(dout * 128 + din) * 3 + kk]);
    }
  } else if (bid < 416) {     // w1: K=128 (kc 4), N=512 (nt 32)
    int tt = bid - 288; int nt = tt / 4, kc = tt % 4;
    for (int i = t; i < 512; i += 256) {
      int lane = i >> 3, j = i & 7;
      int k = kc * 32 + (lane >> 4) * 8 + j;
      int c = nt * 16 + (lane & 15);
      w1F[((nt * 4 + kc) * 64 + lane) * 8 + j] = f2bf(w1[k * 512 + c]);
    }
  } else if (bid < 544) {     // w2: K=512 (kc 16), N=128 (nt 8)
    int tt = bid - 416; int nt = tt / 16, kc = tt % 16;
    for (int i = t; i < 512; i += 256) {
      int lane = i >> 3, j = i & 7;
      int k = kc * 32 + (lane >> 4) * 8 + j;
      int c = nt * 16 + (lane & 15);
      w2F[((nt * 16 + kc) * 64 + lane) * 8 + j] = f2bf(w2[k * 128 + c]);
    }
  } else if (bid < 576) {     // wo: K=128 (kc 4), N=128 (nt 8)
    int tt = bid - 544; int nt = tt / 4, kc = tt % 4;
    for (int i = t; i < 512; i += 256) {
      int lane = i >> 3, j = i & 7;
      int k = kc * 32 + (lane >> 4) * 8 + j;
      int c = nt * 16 + (lane & 15);
      woF[((nt * 4 + kc) * 64 + lane) * 8 + j] = f2bf(wo[k * 128 + c]);
    }
  } else {                    // bias fuse
    int h = bid - 576; float a = alpha[0];
    for (int i = t; i < 400; i += 256) {
      int n = i / 20, m = i % 20;
      biasT[h * 400 + i] = rel[(n - m + 19) * 8 + h] + gb[h * 400 + i] * a;
    }
  }
}

// ======================= SPLIT PATH kernel 1: conv1d-QKV + LN + residual =======================
// Grid 1280 x 768thr (12 waves). M-tile = 128 rows; wave (p, mtp): projection p, rows mtp*32..+32.
// Each wave owns the FULL 128 output cols of its projection -> LayerNorm is wave-local (shfl over
// the 16-lane col groups), no scratch, no extra barriers. Halo masking per (row, kk) at A-frag load.
__global__ __launch_bounds__(768, 3) void conv_qkv(
    const float* __restrict__ x, const unsigned short* __restrict__ WcF,
    const float* __restrict__ lnq_w, const float* __restrict__ lnq_b,
    const float* __restrict__ lnk_w, const float* __restrict__ lnk_b,
    const float* __restrict__ lnv_w, const float* __restrict__ lnv_b,
    unsigned short* __restrict__ qP, unsigned short* __restrict__ kP,
    unsigned short* __restrict__ vP)
{
  __shared__ __align__(16) unsigned short xA[130 * 136];   // rows g0-1 .. g0+128, bf16

  const int t = threadIdx.x;
  const int w = t >> 6, l = t & 63;
  const int l15 = l & 15, l4 = l >> 4;
  const int p = w >> 2, mtp = w & 3;
  const long g0 = (long)blockIdx.x * 128;

  // ---- stage x rows (g0-1 .. g0+128) as bf16 ----
  for (int i = t; i < 130 * 32; i += 768) {
    int r = i >> 5, c4 = i & 31;
    long g = g0 - 1 + r;
    long gc = g < 0 ? 0 : (g > (NROWS - 1) ? (NROWS - 1) : g);
    float4 v = *(const float4*)(x + gc * 128 + c4 * 4);
    ushort4 pk; pk.x = f2bf(v.x); pk.y = f2bf(v.y); pk.z = f2bf(v.z); pk.w = f2bf(v.w);
    *(ushort4*)&xA[r * 136 + c4 * 4] = pk;
  }
  __syncthreads();

  const int rA0 = mtp * 32 + l15;        // A-frag rows (M-dim = l15)
  const int rA1 = rA0 + 16;
  const int nA0 = (int)((g0 + rA0) % 20);
  const int nA1 = (int)((g0 + rA1) % 20);

  f32x4 acc[2][8];
  #pragma unroll
  for (int mt = 0; mt < 2; ++mt)
    #pragma unroll
    for (int nt = 0; nt < 8; ++nt) acc[mt][nt] = (f32x4){0.f, 0.f, 0.f, 0.f};

  const bf16x8 zz = {};
  #pragma unroll
  for (int kk = 0; kk < 3; ++kk) {
    const bool v0 = (kk == 1) || ((kk == 0) ? (nA0 != 0) : (nA0 != 19));
    const bool v1 = (kk == 1) || ((kk == 0) ? (nA1 != 0) : (nA1 != 19));
    const int r0b = (rA0 + kk) * 136, r1b = (rA1 + kk) * 136;
    #pragma unroll
    for (int k4 = 0; k4 < 4; ++k4) {
      int kc = kk * 4 + k4;
      int din0 = k4 * 32 + l4 * 8;
      bf16x8 a0 = *(const bf16x8*)&xA[r0b + din0]; if (!v0) a0 = zz;
      bf16x8 a1 = *(const bf16x8*)&xA[r1b + din0]; if (!v1) a1 = zz;
      #pragma unroll
      for (int nt = 0; nt < 8; ++nt) {
        bf16x8 b = *(const bf16x8*)&WcF[(((p * 8 + nt) * 12 + kc) * 64 + l) * 8];
        acc[0][nt] = __builtin_amdgcn_mfma_f32_16x16x32_bf16(a0, b, acc[0][nt], 0, 0, 0);
        acc[1][nt] = __builtin_amdgcn_mfma_f32_16x16x32_bf16(a1, b, acc[1][nt], 0, 0, 0);
      }
    }
  }

  // ---- epilogue: wave-local LN + residual -> plane (bf16) ----
  const float* lw = (p == 0) ? lnq_w : (p == 1) ? lnk_w : lnv_w;
  const float* lb = (p == 0) ? lnq_b : (p == 1) ? lnk_b : lnv_b;
  unsigned short* plane = (p == 0) ? qP : (p == 1) ? kP : vP;
  const float qscale = (p == 0) ? 0.25f : 1.0f;
  float gw8[8], gb8[8];
  #pragma unroll
  for (int nt = 0; nt < 8; ++nt) { gw8[nt] = lw[nt * 16 + l15]; gb8[nt] = lb[nt * 16 + l15]; }

  #pragma unroll
  for (int mt = 0; mt < 2; ++mt) {
    float s[4], qq[4];
    #pragma unroll
    for (int j = 0; j < 4; ++j) {
      float a0 = 0.f, a1 = 0.f;
      #pragma unroll
      for (int nt = 0; nt < 8; ++nt) { float v = acc[mt][nt][j]; a0 += v; a1 = fmaf(v, v, a1); }
      s[j] = a0; qq[j] = a1;
    }
    #pragma unroll
    for (int off = 1; off < 16; off <<= 1) {
      #pragma unroll
      for (int j = 0; j < 4; ++j) { s[j] += __shfl_xor(s[j], off); qq[j] += __shfl_xor(qq[j], off); }
    }
    long rowb = g0 + mtp * 32 + mt * 16 + l4 * 4;   // D-layout: row = l4*4 + j
    #pragma unroll
    for (int j = 0; j < 4; ++j) {
      float mean = s[j] * (1.f / 128.f);
      float var  = qq[j] * (1.f / 128.f) - mean * mean;
      float inv  = rsqrtf(var + 1e-5f);
      long grow = rowb + j;
      const float* xrow = x + grow * 128;
      #pragma unroll
      for (int nt = 0; nt < 8; ++nt) {
        int col = nt * 16 + l15;
        float o = xrow[col] + (acc[mt][nt][j] - mean) * inv * gw8[nt] + gb8[nt];
        plane[grow * 128 + col] = f2bf(o * qscale);
      }
    }
  }
}

// ======================= SPLIT PATH kernel 2: attention + wo + LN1 =======================
// 2 elements/block, 256 thr. LDS 47104B -> 3 blocks/CU.
//   ks [2][20][136] bf16 @0      (10880)   (ctx aliases this after QK)
//   vs [2][20][136] bf16 @10880  (10880)
//   scr [48][132] f32    @21760  (25344)
__global__ __launch_bounds__(256, 3) void attn_wo(
    const float* __restrict__ x,
    const unsigned short* __restrict__ qP, const unsigned short* __restrict__ kP,
    const unsigned short* __restrict__ vP,
    const unsigned short* __restrict__ woF, const float* __restrict__ biasT,
    const float* __restrict__ bo,
    const float* __restrict__ n1w, const float* __restrict__ n1b,
    unsigned short* __restrict__ xr)
{
  __shared__ __align__(16) char smem[47104];
  unsigned short* ks  = (unsigned short*)smem;
  unsigned short* vs  = (unsigned short*)(smem + 10880);
  unsigned short* ctx = ks;                       // alias after QK completes
  float* scr = (float*)(smem + 21760);

  const int t = threadIdx.x;
  const int w = t >> 6, l = t & 63;
  const int l15 = l & 15, l4 = l >> 4;
  const int eb = blockIdx.x * 2;
  const float* xg = x + (size_t)eb * (NN * DD);

  // ---- stage k,v ----
  for (int i = t; i < 1280; i += 256) {
    int proj = i / 640, r = i % 640;
    int e = r / 320, rr = r % 320;
    int n = rr / 16, c8 = rr % 16;
    const unsigned short* src = (proj == 0 ? kP : vP) + (((size_t)(eb + e) * 20 + n) * 128 + c8 * 8);
    unsigned short* dst = (proj == 0 ? ks : vs) + ((e * 20 + n) * 136 + c8 * 8);
    *(bf16x8*)dst = *(const bf16x8*)src;
  }
  __syncthreads();

  // ---- QK + softmax (both passes before barrier; k fully consumed) ----
  float pm[2][20];
  #pragma unroll
  for (int pass = 0; pass < 2; ++pass) {
    int i = t + pass * 256;
    if (i < 320) {
      int e = i / 160, hh = (i / 20) % 8, n = i % 20;
      const unsigned short* qr = qP + ((size_t)(eb + e) * 20 + n) * 128 + hh * 16;
      bf16x8 qa = *(const bf16x8*)qr, qb = *(const bf16x8*)(qr + 8);
      float q[16];
      #pragma unroll
      for (int j = 0; j < 8; ++j) { q[j] = bf2f((unsigned short)qa[j]); q[8 + j] = bf2f((unsigned short)qb[j]); }
      float bias[20];
      const float* bp = &biasT[(hh * 20 + n) * 20];
      #pragma unroll
      for (int m4 = 0; m4 < 5; ++m4) {
        float4 bv = *(const float4*)(bp + m4 * 4);
        bias[m4 * 4] = bv.x; bias[m4 * 4 + 1] = bv.y; bias[m4 * 4 + 2] = bv.z; bias[m4 * 4 + 3] = bv.w;
      }
      float mx = -1e30f;
      #pragma unroll
      for (int m = 0; m < 20; ++m) {
        const unsigned short* kr = &ks[(e * 20 + m) * 136 + hh * 16];
        bf16x8 ka = *(const bf16x8*)kr, kb = *(const bf16x8*)(kr + 8);
        float sv = bias[m];
        #pragma unroll
        for (int j = 0; j < 8; ++j) {
          sv = fmaf(q[j], bf2f((unsigned short)ka[j]), sv);
          sv = fmaf(q[8 + j], bf2f((unsigned short)kb[j]), sv);
        }
        pm[pass][m] = sv; mx = fmaxf(mx, sv);
      }
      float sum = 0.f;
      #pragma unroll
      for (int m = 0; m < 20; ++m) { pm[pass][m] = __expf(pm[pass][m] - mx); sum += pm[pass][m]; }
      float rs = 1.f / sum;
      #pragma unroll
      for (int m = 0; m < 20; ++m) pm[pass][m] *= rs;
    }
  }
  __syncthreads();

  // ---- PV -> ctx (aliases ks) ----
  #pragma unroll
  for (int pass = 0; pass < 2; ++pass) {
    int i = t + pass * 256;
    if (i < 320) {
      int e = i / 160, hh = (i / 20) % 8, n = i % 20;
      float c[16];
      #pragma unroll
      for (int j = 0; j < 16; ++j) c[j] = 0.f;
      #pragma unroll
      for (int m = 0; m < 20; ++m) {
        const unsigned short* vr = &vs[(e * 20 + m) * 136 + hh * 16];
        bf16x8 va = *(const bf16x8*)vr, vb = *(const bf16x8*)(vr + 8);
        float pv = pm[pass][m];
        #pragma unroll
        for (int j = 0; j < 8; ++j) {
          c[j] = fmaf(pv, bf2f((unsigned short)va[j]), c[j]);
          c[8 + j] = fmaf(pv, bf2f((unsigned short)vb[j]), c[8 + j]);
        }
      }
      bf16x8 c0, c1;
      #pragma unroll
      for (int j = 0; j < 8; ++j) { c0[j] = (short)f2bf(c[j]); c1[j] = (short)f2bf(c[8 + j]); }
      *(bf16x8*)&ctx[(e * 20 + n) * 136 + hh * 16] = c0;
      *(bf16x8*)&ctx[(e * 20 + n) * 136 + hh * 16 + 8] = c1;
    }
  }
  __syncthreads();

  // ---- wo GEMM (ctx @ wo) ----
  int emap[3], nmap[3];
  #pragma unroll
  for (int mt = 0; mt < 3; ++mt) {
    int g = mt * 16 + l15;
    int e = g / 20, n = g - e * 20;
    if (e > 1) { e = 1; n = 19; }
    emap[mt] = e; nmap[mt] = n;
  }
  {
    f32x4 acc[3][2];
    #pragma unroll
    for (int mt = 0; mt < 3; ++mt)
      #pragma unroll
      for (int i = 0; i < 2; ++i) acc[mt][i] = (f32x4){0.f, 0.f, 0.f, 0.f};
    #pragma unroll
    for (int kc = 0; kc < 4; ++kc) {
      bf16x8 a[3], b[2];
      #pragma unroll
      for (int mt = 0; mt < 3; ++mt)
        a[mt] = *(const bf16x8*)&ctx[(emap[mt] * 20 + nmap[mt]) * 136 + kc * 32 + l4 * 8];
      #pragma unroll
      for (int i = 0; i < 2; ++i) {
        int ntg = w * 2 + i;
        b[i] = *(const bf16x8*)&woF[((ntg * 4 + kc) * 64 + l) * 8];
      }
      #pragma unroll
      for (int mt = 0; mt < 3; ++mt)
        #pragma unroll
        for (int i = 0; i < 2; ++i)
          acc[mt][i] = __builtin_amdgcn_mfma_f32_16x16x32_bf16(a[mt], b[i], acc[mt][i], 0, 0, 0);
    }
    #pragma unroll
    for (int mt = 0; mt < 3; ++mt)
      #pragma unroll
      for (int i = 0; i < 2; ++i) {
        int col = (w * 2 + i) * 16 + l15;
        int rbase = mt * 16 + l4 * 4;
        #pragma unroll
        for (int j = 0; j < 4; ++j) scr[(rbase + j) * 132 + col] = acc[mt][i][j];
      }
  }
  __syncthreads();

  // ---- LN1(x + attn_out + bo) -> xr bf16 ----
  for (int r = w; r < 40; r += 4) {
    int e = r / 20, n = r % 20;
    float v0 = scr[r * 132 + l]      + bo[l]      + xg[e * 2560 + n * 128 + l];
    float v1 = scr[r * 132 + 64 + l] + bo[64 + l] + xg[e * 2560 + n * 128 + 64 + l];
    float s = v0 + v1, sq = v0 * v0 + v1 * v1;
    #pragma unroll
    for (int off = 32; off > 0; off >>= 1) { s += __shfl_xor(s, off); sq += __shfl_xor(sq, off); }
    float mean = s * (1.f / 128.f);
    float var  = sq * (1.f / 128.f) - mean * mean;
    float inv  = rsqrtf(var + 1e-5f);
    size_t ro = ((size_t)(eb + e) * 20 + n) * 128;
    xr[ro + l]      = f2bf((v0 - mean) * inv * n1w[l] + n1b[l]);
    xr[ro + 64 + l] = f2bf((v1 - mean) * inv * n1w[64 + l] + n1b[64 + l]);
  }
}

// ======================= FFN + LN2 (both paths) =======================
__global__ __launch_bounds__(256, 3) void ffn_c(
    const unsigned short* __restrict__ xr,
    const unsigned short* __restrict__ w1F, const unsigned short* __restrict__ w2F,
    const float* __restrict__ b1, const float* __restrict__ b2,
    const float* __restrict__ n2w, const float* __restrict__ n2b,
    float* __restrict__ out)
{
  __shared__ __align__(16) char smem[8704 + 33280];
  unsigned short* xrb = (unsigned short*)smem;
  unsigned short* h   = (unsigned short*)(smem + 8704);
  float* sc2          = (float*)(smem + 8704);

  const int t = threadIdx.x;
  const int w = t >> 6, l = t & 63;
  const int l15 = l & 15, l4 = l >> 4;
  const size_t row0 = (size_t)blockIdx.x * 32;

  for (int i = t; i < 512; i += 256) {
    int r = i >> 4, c8 = i & 15;
    *(bf16x8*)&xrb[r * 136 + c8 * 8] = *(const bf16x8*)&xr[(row0 + r) * 128 + c8 * 8];
  }
  __syncthreads();

  {
    f32x4 acc[2][8];
    #pragma unroll
    for (int mt = 0; mt < 2; ++mt)
      #pragma unroll
      for (int i = 0; i < 8; ++i) acc[mt][i] = (f32x4){0.f, 0.f, 0.f, 0.f};
    for (int kc = 0; kc < 4; ++kc) {
      bf16x8 a[2];
      #pragma unroll
      for (int mt = 0; mt < 2; ++mt)
        a[mt] = *(const bf16x8*)&xrb[(mt * 16 + l15) * 136 + kc * 32 + l4 * 8];
      #pragma unroll
      for (int i = 0; i < 8; ++i) {
        int ntg = w * 8 + i;
        bf16x8 b = *(const bf16x8*)&w1F[((ntg * 4 + kc) * 64 + l) * 8];
        #pragma unroll
        for (int mt = 0; mt < 2; ++mt)
          acc[mt][i] = __builtin_amdgcn_mfma_f32_16x16x32_bf16(a[mt], b, acc[mt][i], 0, 0, 0);
      }
    }
    #pragma unroll
    for (int i = 0; i < 8; ++i) {
      int col = (w * 8 + i) * 16 + l15;
      float b1v = b1[col];
      #pragma unroll
      for (int mt = 0; mt < 2; ++mt)
        #pragma unroll
        for (int j = 0; j < 4; ++j) {
          float v = acc[mt][i][j] + b1v;
          h[(mt * 16 + l4 * 4 + j) * 520 + col] = f2bf(gelu_t(v));
        }
    }
  }
  __syncthreads();

  f32x4 acc2[2][2];
  #pragma unroll
  for (int mt = 0; mt < 2; ++mt)
    #pragma unroll
    for (int i = 0; i < 2; ++i) acc2[mt][i] = (f32x4){0.f, 0.f, 0.f, 0.f};
  for (int kc = 0; kc < 16; ++kc) {
    bf16x8 a[2];
    #pragma unroll
    for (int mt = 0; mt < 2; ++mt)
      a[mt] = *(const bf16x8*)&h[(mt * 16 + l15) * 520 + kc * 32 + l4 * 8];
    #pragma unroll
    for (int i = 0; i < 2; ++i) {
      int ntg = w * 2 + i;
      bf16x8 b = *(const bf16x8*)&w2F[((ntg * 16 + kc) * 64 + l) * 8];
      #pragma unroll
      for (int mt = 0; mt < 2; ++mt)
        acc2[mt][i] = __builtin_amdgcn_mfma_f32_16x16x32_bf16(a[mt], b, acc2[mt][i], 0, 0, 0);
    }
  }
  __syncthreads();

  #pragma unroll
  for (int mt = 0; mt < 2; ++mt)
    #pragma unroll
    for (int i = 0; i < 2; ++i) {
      int col = (w * 2 + i) * 16 + l15;
      int rbase = mt * 16 + l4 * 4;
      #pragma unroll
      for (int j = 0; j < 4; ++j) sc2[(rbase + j) * 132 + col] = acc2[mt][i][j];
    }
  __syncthreads();

  for (int r = w; r < 32; r += 4) {
    float v0 = sc2[r * 132 + l]      + b2[l]      + bf2f(xrb[r * 136 + l]);
    float v1 = sc2[r * 132 + 64 + l] + b2[64 + l] + bf2f(xrb[r * 136 + 64 + l]);
    float s = v0 + v1, sq = v0 * v0 + v1 * v1;
    #pragma unroll
    for (int off = 32; off > 0; off >>= 1) { s += __shfl_xor(s, off); sq += __shfl_xor(sq, off); }
    float mean = s * (1.f / 128.f);
    float var  = sq * (1.f / 128.f) - mean * mean;
    float inv  = rsqrtf(var + 1e-5f);
    out[(row0 + r) * 128 + l]      = (v0 - mean) * inv * n2w[l] + n2b[l];
    out[(row0 + r) * 128 + 64 + l] = (v1 - mean) * inv * n2w[64 + l] + n2b[64 + l];
  }
}

// ======================= FALLBACK (round-2, known good): fused conv+attn+wo+LN1 =======================
__global__ __launch_bounds__(256, 2) void fused_ab(
    const float* __restrict__ x,
    const unsigned short* __restrict__ WcF, const unsigned short* __restrict__ woF,
    const float* __restrict__ biasT,
    const float* __restrict__ lnq_w, const float* __restrict__ lnq_b,
    const float* __restrict__ lnk_w, const float* __restrict__ lnk_b,
    const float* __restrict__ lnv_w, const float* __restrict__ lnv_b,
    const float* __restrict__ bo,
    const float* __restrict__ n1w, const float* __restrict__ n1b,
    unsigned short* __restrict__ xr)
{
  __shared__ __align__(16) char smem[80832];
  unsigned short* qkv = (unsigned short*)smem;
  unsigned short* ctx = (unsigned short*)(smem + 32640);
  unsigned short* xA  = (unsigned short*)(smem + 43520);
  float* scr = (float*)(smem + 55488);

  const int t = threadIdx.x;
  const int w = t >> 6, l = t & 63;
  const int l15 = l & 15, l4 = l >> 4;
  const int eb = blockIdx.x * 2;
  const float* xg = x + (size_t)eb * (NN * DD);

  int emap[3], nmap[3];
  #pragma unroll
  for (int mt = 0; mt < 3; ++mt) {
    int g = mt * 16 + l15;
    int e = g / 20, n = g - e * 20;
    if (e > 1) { e = 1; n = 19; }
    emap[mt] = e; nmap[mt] = n;
  }

  for (int i = t; i < 2 * 2 * 136; i += 256) {
    int e = i / 272, rr = i % 272; int pr = rr / 136, c = rr % 136;
    xA[(e * 22 + pr * 21) * 136 + c] = 0;
  }
  for (int i = t; i < 1280; i += 256) {
    int e = i / 640, r2 = i % 640; int n = r2 / 32, c4 = r2 % 32;
    float4 v = *(const float4*)(xg + e * 2560 + n * 128 + c4 * 4);
    unsigned short* dst = &xA[(e * 22 + n + 1) * 136 + c4 * 4];
    ushort4 pk; pk.x = f2bf(v.x); pk.y = f2bf(v.y); pk.z = f2bf(v.z); pk.w = f2bf(v.w);
    *(ushort4*)dst = pk;
  }
  __syncthreads();

  for (int p = 0; p < 3; ++p) {
    const float* lw = (p == 0) ? lnq_w : (p == 1) ? lnk_w : lnv_w;
    const float* lb = (p == 0) ? lnq_b : (p == 1) ? lnk_b : lnv_b;
    f32x4 acc[3][2];
    #pragma unroll
    for (int mt = 0; mt < 3; ++mt)
      #pragma unroll
      for (int i = 0; i < 2; ++i) acc[mt][i] = (f32x4){0.f, 0.f, 0.f, 0.f};

    for (int kc = 0; kc < 12; ++kc) {
      int kk = kc >> 2;
      int din0 = (kc & 3) * 32 + l4 * 8;
      bf16x8 a[3], b[2];
      #pragma unroll
      for (int mt = 0; mt < 3; ++mt)
        a[mt] = *(const bf16x8*)&xA[(emap[mt] * 22 + nmap[mt] + kk) * 136 + din0];
      #pragma unroll
      for (int i = 0; i < 2; ++i) {
        int ntg = p * 8 + w * 2 + i;
        b[i] = *(const bf16x8*)&WcF[((ntg * 12 + kc) * 64 + l) * 8];
      }
      #pragma unroll
      for (int mt = 0; mt < 3; ++mt)
        #pragma unroll
        for (int i = 0; i < 2; ++i)
          acc[mt][i] = __builtin_amdgcn_mfma_f32_16x16x32_bf16(a[mt], b[i], acc[mt][i], 0, 0, 0);
    }
    #pragma unroll
    for (int mt = 0; mt < 3; ++mt)
      #pragma unroll
      for (int i = 0; i < 2; ++i) {
        int col = (w * 2 + i) * 16 + l15;
        int rbase = mt * 16 + l4 * 4;
        #pragma unroll
        for (int j = 0; j < 4; ++j) scr[(rbase + j) * 132 + col] = acc[mt][i][j];
      }
    __syncthreads();
    for (int r = w; r < 40; r += 4) {
      float v0 = scr[r * 132 + l], v1 = scr[r * 132 + 64 + l];
      float s = v0 + v1, sq = v0 * v0 + v1 * v1;
      #pragma unroll
      for (int off = 32; off > 0; off >>= 1) { s += __shfl_xor(s, off); sq += __shfl_xor(sq, off); }
      float mean = s * (1.f / 128.f);
      float var  = sq * (1.f / 128.f) - mean * mean;
      float inv  = rsqrtf(var + 1e-5f);
      int e = r / 20, n = r % 20;
      float x0 = xg[e * 2560 + n * 128 + l], x1 = xg[e * 2560 + n * 128 + 64 + l];
      float o0 = x0 + (v0 - mean) * inv * lw[l] + lb[l];
      float o1 = x1 + (v1 - mean) * inv * lw[64 + l] + lb[64 + l];
      if (p == 0) { o0 *= 0.25f; o1 *= 0.25f; }
      qkv[((p * 2 + e) * 20 + n) * 136 + l] = f2bf(o0);
      qkv[((p * 2 + e) * 20 + n) * 136 + 64 + l] = f2bf(o1);
    }
    __syncthreads();
  }

  #pragma unroll
  for (int ii = 0; ii < 2; ++ii) {
    int i = (ii == 0) ? l : (l + 64);
    if (i < 80) {
      int rid = w * 80 + i;
      int e = rid / 160, hh = (rid / 20) % 8, n = rid % 20;
      float q[16];
      {
        const unsigned short* qr = &qkv[(e * 20 + n) * 136 + hh * 16];
        bf16x8 qa = *(const bf16x8*)qr, qb = *(const bf16x8*)(qr + 8);
        #pragma unroll
        for (int j = 0; j < 8; ++j) { q[j] = bf2f((unsigned short)qa[j]); q[8 + j] = bf2f((unsigned short)qb[j]); }
      }
      float bias[20];
      const float* bp = &biasT[(hh * 20 + n) * 20];
      #pragma unroll
      for (int m4 = 0; m4 < 5; ++m4) {
        float4 bv = *(const float4*)(bp + m4 * 4);
        bias[m4 * 4] = bv.x; bias[m4 * 4 + 1] = bv.y; bias[m4 * 4 + 2] = bv.z; bias[m4 * 4 + 3] = bv.w;
      }
      float pmv[20]; float mx = -1e30f;
      #pragma unroll
      for (int m = 0; m < 20; ++m) {
        const unsigned short* kr = &qkv[((2 + e) * 20 + m) * 136 + hh * 16];
        bf16x8 ka = *(const bf16x8*)kr, kb = *(const bf16x8*)(kr + 8);
        float sv = bias[m];
        #pragma unroll
        for (int j = 0; j < 8; ++j) {
          sv = fmaf(q[j], bf2f((unsigned short)ka[j]), sv);
          sv = fmaf(q[8 + j], bf2f((unsigned short)kb[j]), sv);
        }
        pmv[m] = sv; mx = fmaxf(mx, sv);
      }
      float sum = 0.f;
      #pragma unroll
      for (int m = 0; m < 20; ++m) { pmv[m] = __expf(pmv[m] - mx); sum += pmv[m]; }
      float rs = 1.f / sum;
      float c[16];
      #pragma unroll
      for (int j = 0; j < 16; ++j) c[j] = 0.f;
      #pragma unroll
      for (int m = 0; m < 20; ++m) {
        const unsigned short* vr = &qkv[((4 + e) * 20 + m) * 136 + hh * 16];
        bf16x8 va = *(const bf16x8*)vr, vb = *(const bf16x8*)(vr + 8);
        float pv = pmv[m];
        #pragma unroll
        for (int j = 0; j < 8; ++j) {
          c[j] = fmaf(pv, bf2f((unsigned short)va[j]), c[j]);
          c[8 + j] = fmaf(pv, bf2f((unsigned short)vb[j]), c[8 + j]);
        }
      }
      bf16x8 c0, c1;
      #pragma unroll
      for (int j = 0; j < 8; ++j) {
        c0[j] = (short)f2bf(c[j] * rs);
        c1[j] = (short)f2bf(c[8 + j] * rs);
      }
      *(bf16x8*)&ctx[(e * 20 + n) * 136 + hh * 16] = c0;
      *(bf16x8*)&ctx[(e * 20 + n) * 136 + hh * 16 + 8] = c1;
    }
  }
  __syncthreads();

  {
    f32x4 acc[3][2];
    #pragma unroll
    for (int mt = 0; mt < 3; ++mt)
      #pragma unroll
      for (int i = 0; i < 2; ++i) acc[mt][i] = (f32x4){0.f, 0.f, 0.f, 0.f};
    for (int kc = 0; kc < 4; ++kc) {
      bf16x8 a[3], b[2];
      #pragma unroll
      for (int mt = 0; mt < 3; ++mt)
        a[mt] = *(const bf16x8*)&ctx[(emap[mt] * 20 + nmap[mt]) * 136 + kc * 32 + l4 * 8];
      #pragma unroll
      for (int i = 0; i < 2; ++i) {
        int ntg = w * 2 + i;
        b[i] = *(const bf16x8*)&woF[((ntg * 4 + kc) * 64 + l) * 8];
      }
      #pragma unroll
      for (int mt = 0; mt < 3; ++mt)
        #pragma unroll
        for (int i = 0; i < 2; ++i)
          acc[mt][i] = __builtin_amdgcn_mfma_f32_16x16x32_bf16(a[mt], b[i], acc[mt][i], 0, 0, 0);
    }
    #pragma unroll
    for (int mt = 0; mt < 3; ++mt)
      #pragma unroll
      for (int i = 0; i < 2; ++i) {
        int col = (w * 2 + i) * 16 + l15;
        int rbase = mt * 16 + l4 * 4;
        #pragma unroll
        for (int j = 0; j < 4; ++j) scr[(rbase + j) * 132 + col] = acc[mt][i][j];
      }
  }
  __syncthreads();

  for (int r = w; r < 40; r += 4) {
    int e = r / 20, n = r % 20;
    float v0 = scr[r * 132 + l]      + bo[l]      + xg[e * 2560 + n * 128 + l];
    float v1 = scr[r * 132 + 64 + l] + bo[64 + l] + xg[e * 2560 + n * 128 + 64 + l];
    float s = v0 + v1, sq = v0 * v0 + v1 * v1;
    #pragma unroll
    for (int off = 32; off > 0; off >>= 1) { s += __shfl_xor(s, off); sq += __shfl_xor(sq, off); }
    float mean = s * (1.f / 128.f);
    float var  = sq * (1.f / 128.f) - mean * mean;
    float inv  = rsqrtf(var + 1e-5f);
    size_t ro = ((size_t)(eb + e) * 20 + n) * 128;
    xr[ro + l]      = f2bf((v0 - mean) * inv * n1w[l] + n1b[l]);
    xr[ro + 64 + l] = f2bf((v1 - mean) * inv * n1w[64 + l] + n1b[64 + l]);
  }
}

extern "C" void kernel_launch(void* const* d_in, const int* in_sizes, int n_in,
                              void* d_out, int out_size, void* d_ws, size_t ws_size,
                              hipStream_t stream) {
  const float* x     = (const float*)d_in[0];
  const float* wq    = (const float*)d_in[1];
  const float* wk    = (const float*)d_in[2];
  const float* wv    = (const float*)d_in[3];
  const float* lnq_w = (const float*)d_in[4];
  const float* lnq_b = (const float*)d_in[5];
  const float* lnk_w = (const float*)d_in[6];
  const float* lnk_b = (const float*)d_in[7];
  const float* lnv_w = (const float*)d_in[8];
  const float* lnv_b = (const float*)d_in[9];
  const float* rel   = (const float*)d_in[10];
  const float* gb    = (const float*)d_in[11];
  const float* alpha = (const float*)d_in[12];
  const float* wo    = (const float*)d_in[13];
  const float* bo    = (const float*)d_in[14];
  const float* w1    = (const float*)d_in[15];
  const float* b1    = (const float*)d_in[16];
  const float* w2    = (const float*)d_in[17];
  const float* b2    = (const float*)d_in[18];
  const float* n1w   = (const float*)d_in[19];
  const float* n1b   = (const float*)d_in[20];
  const float* n2w   = (const float*)d_in[21];
  const float* n2b   = (const float*)d_in[22];
  float* out = (float*)d_out;

  // ws layout: WcF | w1F | w2F | woF | biasT  (602624 B), then xr (41943040 B), then q plane.
  unsigned short* WcF = (unsigned short*)d_ws;     // 147456 us
  unsigned short* w1F = WcF + 147456;              // 65536
  unsigned short* w2F = w1F + 65536;               // 65536
  unsigned short* woF = w2F + 65536;               // 16384
  float* biasT = (float*)(woF + 16384);            // 3200 f32 -> ends at 602624 B
  unsigned short* xr = (unsigned short*)((char*)d_ws + 602624);

  const size_t NEED2 = 602624ULL + 41943040ULL;                // round-2 fused path
  const size_t NEED3 = NEED2 + 41943040ULL;                    // + q plane (k,v live in d_out)

  hipLaunchKernelGGL(prep2, dim3(584), dim3(256), 0, stream,
                     wq, wk, wv, w1, w2, wo, rel, gb, alpha, WcF, w1F, w2F, woF, biasT);

  if (ws_size >= NEED3) {
    unsigned short* qP = (unsigned short*)((char*)d_ws + NEED2);
    unsigned short* kP = (unsigned short*)d_out;                 // d_out as scratch: k plane
    unsigned short* vP = kP + (size_t)NROWS * 128;               // v plane (exactly fills d_out)

    hipLaunchKernelGGL(conv_qkv, dim3(NROWS / 128), dim3(768), 0, stream,
                       x, WcF, lnq_w, lnq_b, lnk_w, lnk_b, lnv_w, lnv_b, qP, kP, vP);
    hipLaunchKernelGGL(attn_wo, dim3(NB / 2), dim3(256), 0, stream,
                       x, qP, kP, vP, woF, biasT, bo, n1w, n1b, xr);
  } else {
    hipLaunchKernelGGL(fused_ab, dim3(NB / 2), dim3(256), 0, stream,
                       x, WcF, woF, biasT, lnq_w, lnq_b, lnk_w, lnk_b, lnv_w, lnv_b,
                       bo, n1w, n1b, xr);
  }
  hipLaunchKernelGGL(ffn_c, dim3(NB * NN / 32), dim3(256), 0, stream,
                     xr, w1F, w2F, b1, b2, n2w, n2b, out);
}